// Round 6
// baseline (614.696 us; speedup 1.0000x reference)
//
#include <hip/hip_runtime.h>
#include <math.h>

// ---------------- FDTD fully-fused persistent kernel ----------------
// 400x400 grid, 300 steps, batch 2. Tile: 40x40 interior + halo 12 -> 64x64 ext.
// ONE kernel does all 25 rounds x 12 steps; fields live in registers throughout.
// Block = 512 threads = 8 waves; wave w owns ext rows [8w,8w+8), lane = ext col.
// Intra-round: column neighbors via __shfl, wave-boundary rows via ping-pong LDS
// slots guarded by monotone per-wave step flags (R5 scheme, proven bitwise-exact).
// Inter-round: blocks write their 40x40 interior into ping-pong global buffers
// P[r&1], release a per-tile device-scope flag, acquire-spin on 8 neighbors'
// flags, then reload the 12-wide halo ring. Ping-pong + publish-before-spin
// (separated by __syncthreads) makes it deadlock-free and overwrite-safe at the
// <=1-round skew the dependencies allow. 200 blocks <= 256 CUs -> co-resident.
#define NXg 400
#define NYg 400
#define NN (NXg * NYg)
#define SRC_I 30
#define DET_I 370
#define TILE_B 40
#define HALO 12
#define NTI 10          // tiles per dim (10*40 = 400 exact)
#define ROUNDS 25
#define RSTEPS 12
#define NB 2
#define XSLOT 576       // 9 slots * 64 lanes (ghost slots = zeros)
#define NTILES (NB * NTI * NTI)   // 200 flag entries

static constexpr float DT_F     = (float)(0.5 * 25e-9 / 299792458.0);     // COURANT*DX/C0
static constexpr float PERIOD_F = (float)(1550e-9 / 299792458.0);         // WAVELENGTH/C0
static constexpr float TWOPI_F  = (float)(2.0 * 3.14159265358979323846);
static constexpr float PI_F     = (float)3.14159265358979323846;

// shared helper so the redundant "row above" Hy update compiles identically
__device__ __forceinline__ float hupd(float damp, float h, float d) {
    return damp * (h + 0.5f * d);
}

// ---- one-time (per call) setup: rc = COURANT/eps, damp profile, zero tile flags ----
__global__ void fdtd_setup(const float* __restrict__ radius,
                           float* __restrict__ rc_g, float* __restrict__ px_g,
                           int* __restrict__ flg)
{
    __shared__ float rsh[64];
    if (threadIdx.x < 64) {
        float r = radius[threadIdx.x];
        rsh[threadIdx.x] = (r < 0.3f) ? 0.f : r;
    }
    __syncthreads();

    int idx = blockIdx.x * blockDim.x + threadIdx.x;
    if (idx >= NN) return;
    int i = idx / NYg, j = idx % NYg;

    if (idx < NTILES) flg[idx] = 0;   // ws is poisoned 0xAA every call

    float eps = 1.0f;
    int dj = j - 70;  // port columns: [70..89],[150..169],[230..249],[310..329]
    bool port = (dj >= 0) && (dj < 260) && ((dj % 80) < 20);
    if (port && (i < SRC_I || i >= DET_I)) eps = 2.8f;
    if (i >= 80 && i < 320 && j >= 80 && j < 320) {
        // design region: 8x8 circles, spacing 30, centers 15+30k; r<0.3 -> 0
        float x = (float)(i - 80), y = (float)(j - 80);
        bool inside = false;
        #pragma unroll 8
        for (int a = 0; a < 64; ++a) {
            float r = rsh[a];
            float cx = (float)(15 + 30 * (a >> 3));
            float cy = (float)(15 + 30 * (a & 7));
            float dx = x - cx, dy = y - cy;
            if (dx * dx + dy * dy <= r * r) inside = true;
        }
        eps = inside ? 1.0f : 2.8f;
    }
    rc_g[idx] = 0.5f / eps;

    if (idx < NXg) {
        // damp profile in double, then cast: matches numpy f64 exp -> f32
        double prof = 1.0;
        if (idx < 10) {
            double rmp = (10.0 - (double)idx - 0.5) / 10.0;
            prof = exp(-0.5 * rmp * rmp * rmp);
        } else if (idx >= NXg - 10) {
            double rmp = ((double)(idx - (NXg - 10)) + 0.5) / 10.0;
            prof = exp(-0.5 * rmp * rmp * rmp);
        }
        px_g[idx] = (float)prof;
    }
}

// ---- the fused kernel: 300 steps, registers persistent, strip exchange between rounds ----
__global__ __launch_bounds__(512)
void fdtd_fused(const float* __restrict__ phase,
                const float* __restrict__ rc_g, const float* __restrict__ px_g,
                float* __restrict__ Pez, float* __restrict__ Phx,
                float* __restrict__ Phy, int* __restrict__ flg,
                float* __restrict__ out)
{
    // intra-round ping-pong wave-boundary exchange buffers (R5 scheme)
    __shared__ float xEz0[2][XSLOT];   // slot w   = wave w's Ez row0; slot 8 ghost
    __shared__ float xEzL[2][XSLOT];   // slot w+1 = wave w's Ez row7; slot 0 ghost
    __shared__ float xHyL[2][XSLOT];   // slot w+1 = wave w's Hy row7 (pre-update)
    __shared__ int fEz0[9];            // producer w -> fEz0[w];   ghost index 8
    __shared__ int fEzL[9];            // producer w -> fEzL[w+1]; ghost index 0

    const int tid = threadIdx.x;
    const int w   = tid >> 6;
    const int lj  = tid & 63;
    const int bx  = blockIdx.x;        // row tile
    const int by  = blockIdx.y;        // col tile
    const int b   = blockIdx.z;
    const int gx0 = bx * TILE_B - HALO;
    const int gy0 = by * TILE_B - HALO;
    const int gj  = gy0 + lj;
    const int gib = gx0 + 8 * w;       // global row of register r=0
    const size_t bb   = (size_t)b * NN;
    const size_t POFF = (size_t)NB * NN;   // parity stride in P buffers

    // ---- neighbor flag bookkeeping (tids 0..7 spin; tid 0 publishes) ----
    const int me = (b * NTI + bx) * NTI + by;
    int  nbi = 0; bool nbv = false;
    if (tid < 8) {
        const int drc[8][2] = {{-1,-1},{-1,0},{-1,1},{0,-1},{0,1},{1,-1},{1,0},{1,1}};
        const int nr = bx + drc[tid][0], nc = by + drc[tid][1];
        nbv = (nr >= 0) && (nr < NTI) && (nc >= 0) && (nc < NTI);
        nbi = (b * NTI + nr) * NTI + nc;
    }

    // ---- init LDS ghosts + flags once ----
    if (tid < 64) {
        #pragma unroll
        for (int p = 0; p < 2; ++p) {
            xEz0[p][512 + tid] = 0.f;   // ghost slot 8 (below wave 7)
            xEzL[p][tid] = 0.f;         // ghost slot 0 (above wave 0)
            xHyL[p][tid] = 0.f;
        }
        if (tid < 9) { fEz0[tid] = -1; fEzL[tid] = -1; }
        if (tid == 0) { fEz0[8] = 0x7fffffff; fEzL[0] = 0x7fffffff; }
    }

    const bool jin = (gj >= 0) && (gj < NYg);
    const float pyv = jin ? px_g[gj] : 0.f;

    // ---- initial state: zeros (t=0); static coefficients from global ----
    float Ez[8], Hx[8], Hy[8], rc[8], dmp[8];
    #pragma unroll
    for (int r = 0; r < 8; ++r) {
        const int gi = gib + r;
        const bool in = jin && (gi >= 0) && (gi < NXg);
        Ez[r] = 0.f; Hx[r] = 0.f; Hy[r] = 0.f;
        if (in) {
            rc[r]  = rc_g[(size_t)gi * NYg + gj];
            dmp[r] = px_g[gi] * pyv;
        } else { rc[r] = 0.5f; dmp[r] = 0.f; }
    }
    float dmpA = 0.f;   // damp of the row just above this wave's rows
    { const int giA = gib - 1; if (jin && giA >= 0 && giA < NXg) dmpA = px_g[giA] * pyv; }

    const int djp = gj - 70;
    const int pport = (djp >= 0 && djp < 260 && (djp % 80) < 20) ? (djp / 80) : -1;
    const float phv = (pport >= 0) ? phase[b * 4 + pport] : 0.f;
    const bool gYlt = (gj < NYg - 1);
    const bool gYgt = (gj > 0);
    const bool hasSrc = (gib <= SRC_I) && (SRC_I < gib + 8);

    __syncthreads();   // LDS ghosts + flag init visible

    // ---- publish step-0 boundary data, release LDS flags (gs = 0) ----
    xEz0[0][(w << 6) + lj] = Ez[0];
    xEzL[0][((w + 1) << 6) + lj] = Ez[7];
    xHyL[0][((w + 1) << 6) + lj] = Hy[7];
    if (lj == 0) {
        __hip_atomic_store(&fEz0[w],     0, __ATOMIC_RELEASE, __HIP_MEMORY_SCOPE_WORKGROUP);
        __hip_atomic_store(&fEzL[w + 1], 0, __ATOMIC_RELEASE, __HIP_MEMORY_SCOPE_WORKGROUP);
    }

    for (int rnd = 0; rnd < ROUNDS; ++rnd) {
        const int t0 = rnd * RSTEPS;

        for (int s = 0; s < RSTEPS; ++s) {
            const int gs = t0 + s;
            const int p  = gs & 1;
            // acquire-spin: neighbor waves' step-gs data ready
            while (__hip_atomic_load(&fEz0[w + 1], __ATOMIC_ACQUIRE, __HIP_MEMORY_SCOPE_WORKGROUP) < gs) {}
            const float ezB  = xEz0[p][((w + 1) << 6) + lj];
            while (__hip_atomic_load(&fEzL[w], __ATOMIC_ACQUIRE, __HIP_MEMORY_SCOPE_WORKGROUP) < gs) {}
            const float ezAL = xEzL[p][(w << 6) + lj];
            const float hyAL = xHyL[p][(w << 6) + lj];
            // redundant Hy update of the row above — bitwise-identical inputs/expression
            const float dexA = (gib - 1 < NXg - 1) ? (Ez[0] - ezAL) : 0.f;
            const float hyA  = hupd(dmpA, hyAL, dexA);

            // ---- H update (registers + shuffles) ----
            float ezn[8];
            #pragma unroll
            for (int r = 0; r < 7; ++r) ezn[r] = Ez[r + 1];
            ezn[7] = ezB;
            #pragma unroll
            for (int r = 0; r < 8; ++r) {
                const int gi = gib + r;
                const float ezr = __shfl_down(Ez[r], 1, 64);
                const float dey = gYlt ? (ezr - Ez[r]) : 0.f;
                const float dex = (gi < NXg - 1) ? (ezn[r] - Ez[r]) : 0.f;
                Hx[r] = hupd(dmp[r], Hx[r], -dey);
                Hy[r] = hupd(dmp[r], Hy[r], dex);
            }

            // ---- E update + soft source ----
            const float tf = (float)gs;
            float hyprev = hyA;
            #pragma unroll
            for (int r = 0; r < 8; ++r) {
                const int gi = gib + r;
                const float hxl = __shfl_up(Hx[r], 1, 64);
                const float dhyx = (gi > 0) ? (Hy[r] - hyprev) : 0.f;
                const float dhxy = gYgt ? (Hx[r] - hxl) : 0.f;
                float ez = dmp[r] * (Ez[r] + rc[r] * (dhyx - dhxy));
                if (hasSrc && (gi == SRC_I) && (pport >= 0)) {
                    const float a = tf * DT_F;                  // JAX f32 op order
                    ez += sinf(TWOPI_F * a / PERIOD_F + PI_F * phv);
                }
                Ez[r] = ez;
                hyprev = Hy[r];
            }

            // ---- publish step gs+1 boundary data, release LDS flags ----
            if (s < RSTEPS - 1) {
                const int q = (gs + 1) & 1;
                xEz0[q][(w << 6) + lj] = Ez[0];
                xEzL[q][((w + 1) << 6) + lj] = Ez[7];
                xHyL[q][((w + 1) << 6) + lj] = Hy[7];
                if (lj == 0) {
                    __hip_atomic_store(&fEz0[w],     gs + 1, __ATOMIC_RELEASE, __HIP_MEMORY_SCOPE_WORKGROUP);
                    __hip_atomic_store(&fEzL[w + 1], gs + 1, __ATOMIC_RELEASE, __HIP_MEMORY_SCOPE_WORKGROUP);
                }
            }
        }

        // ---- inter-round strip exchange (not after the last round) ----
        if (rnd < ROUNDS - 1) {
            const size_t par = (size_t)(rnd & 1) * POFF;
            // 1. store my interior into P[rnd&1]
            if (lj >= HALO && lj < HALO + TILE_B) {
                #pragma unroll
                for (int r = 0; r < 8; ++r) {
                    const int li = (w << 3) + r;
                    if (li >= HALO && li < HALO + TILE_B) {
                        const int gi = gx0 + li;
                        const size_t go = par + bb + (size_t)gi * NYg + gj;
                        Pez[go] = Ez[r]; Phx[go] = Hx[r]; Phy[go] = Hy[r];
                    }
                }
            }
            __syncthreads();                 // all strips retired to L2
            // 2. publish my flag (device-scope release: L2 writeback + store)
            if (tid == 0)
                __hip_atomic_store(&flg[me], rnd + 1, __ATOMIC_RELEASE, __HIP_MEMORY_SCOPE_AGENT);
            __syncthreads();                 // publish strictly before any spin (deadlock-free)
            // 3. acquire-spin on 8 neighbors
            if (tid < 8 && nbv) {
                while (__hip_atomic_load(&flg[nbi], __ATOMIC_ACQUIRE, __HIP_MEMORY_SCOPE_AGENT) < rnd + 1) {
                    __builtin_amdgcn_s_sleep(1);
                }
            }
            __syncthreads();                 // halo data now coherent for all waves
            // 4. reload halo ring (interior registers persist)
            #pragma unroll
            for (int r = 0; r < 8; ++r) {
                const int li = (w << 3) + r;
                const int gi = gib + r;
                const bool interior = (li >= HALO) && (li < HALO + TILE_B) &&
                                      (lj >= HALO) && (lj < HALO + TILE_B);
                const bool in = jin && (gi >= 0) && (gi < NXg);
                if (in && !interior) {
                    const size_t go = par + bb + (size_t)gi * NYg + gj;
                    Ez[r] = Pez[go]; Hx[r] = Phx[go]; Hy[r] = Phy[go];
                }
            }
            // 5. publish step t0+12 boundary data (slot 0; (t0+12) even), release flags
            {
                const int gs2 = t0 + RSTEPS;
                const int q = gs2 & 1;
                xEz0[q][(w << 6) + lj] = Ez[0];
                xEzL[q][((w + 1) << 6) + lj] = Ez[7];
                xHyL[q][((w + 1) << 6) + lj] = Hy[7];
                if (lj == 0) {
                    __hip_atomic_store(&fEz0[w],     gs2, __ATOMIC_RELEASE, __HIP_MEMORY_SCOPE_WORKGROUP);
                    __hip_atomic_store(&fEzL[w + 1], gs2, __ATOMIC_RELEASE, __HIP_MEMORY_SCOPE_WORKGROUP);
                }
            }
        }
    }

    // ---- detector: row 370 lives in row-tile 9 at ext li=22 -> wave 2, r=6 ----
    if (bx == 9 && w == 2) {
        if (lj >= HALO && lj < HALO + TILE_B && pport >= 0) {
            const int k = gj - (80 * pport + 70);
            out[b * 80 + pport * 20 + k] = Ez[6];
        }
    }
}

extern "C" void kernel_launch(void* const* d_in, const int* in_sizes, int n_in,
                              void* d_out, int out_size, void* d_ws, size_t ws_size,
                              hipStream_t stream)
{
    const float* phase  = (const float*)d_in[0];   // (2,4) f32
    const float* radius = (const float*)d_in[1];   // (8,8) f32
    float* ws = (float*)d_ws;
    // workspace (floats): Pez[2][2*NN] | Phx[2][2*NN] | Phy[2][2*NN] | rc[NN] | px[400+pad] | flg[200]
    float* Pez  = ws;                   // 4*NN
    float* Phx  = ws + 4 * NN;          // 4*NN
    float* Phy  = ws + 8 * NN;          // 4*NN
    float* rc_g = ws + 12 * NN;         // NN
    float* px_g = ws + 13 * NN;         // 512
    int*   flg  = (int*)(ws + 13 * NN + 512);

    fdtd_setup<<<(NN + 255) / 256, 256, 0, stream>>>(radius, rc_g, px_g, flg);

    dim3 grid(NTI, NTI, NB);
    fdtd_fused<<<grid, 512, 0, stream>>>(phase, rc_g, px_g, Pez, Phx, Phy, flg, (float*)d_out);
}